// Round 3
// baseline (1978.558 us; speedup 1.0000x reference)
//
#include <hip/hip_runtime.h>

#define COMP(v,j) ((j)==0?(v).x:((j)==1?(v).y:((j)==2?(v).z:(v).w)))

// ---- Pass 1: per-row degree counters: hi32 = #non-self edges, lo32 = sum cc[col]
__global__ void k_deg(const int* __restrict__ ei, const int* __restrict__ cc,
                      unsigned long long* __restrict__ deg, int E) {
    int e = blockIdx.x * blockDim.x + threadIdx.x;
    if (e >= E) return;
    int c = ei[e];       // col = edge_index[0]
    int r = ei[E + e];   // row = edge_index[1]
    if (r != c) {
        unsigned long long add = 0x100000000ULL + (unsigned long long)(cc[c] & 1);
        atomicAdd(&deg[r], add);
    }
}

// ---- Pass 2: D^-0.5 for the 4 norms + CSR offset allocation (wave scan, 1 atomic/wave)
__global__ void k_dinv_alloc(const unsigned long long* __restrict__ deg,
                             const int* __restrict__ cc,
                             float* __restrict__ dl, float* __restrict__ dh,
                             float* __restrict__ dll, float* __restrict__ dhh,
                             int* __restrict__ off, int* __restrict__ cur,
                             unsigned* __restrict__ total, int n) {
    int i = blockIdx.x * blockDim.x + threadIdx.x;
    int lane = threadIdx.x & 63;
    unsigned long long d = (i < n) ? deg[i] : 0ULL;
    int cnt = (int)(d >> 32);
    int ccs = (int)(d & 0xffffffffULL);
    if (i < n) {
        float c = (float)cc[i];
        float fc = (float)cnt, fs = (float)ccs;
        dl[i]  = rsqrtf(c * fc + 1.0f);
        dh[i]  = rsqrtf((1.0f - c) * fc + 1.0f);
        dll[i] = rsqrtf(fs + 1.0f);
        dhh[i] = rsqrtf(fc - fs + 1.0f);
    }
    // wave-level inclusive scan of cnt
    int s = cnt;
    #pragma unroll
    for (int dlt = 1; dlt < 64; dlt <<= 1) {
        int t = __shfl_up(s, dlt, 64);
        if (lane >= dlt) s += t;
    }
    int wtot = __shfl(s, 63, 64);
    unsigned base = 0;
    if (lane == 0) base = atomicAdd(total, (unsigned)wtot);
    base = __shfl(base, 0, 64);
    if (i < n) {
        int o = (int)base + s - cnt;   // exclusive prefix within wave + wave base
        off[i] = o;
        cur[i] = o;
    }
}

// ---- CSR fill: slot per edge via per-row cursor (cur ends at off+cnt = row end)
__global__ void k_fill(const int* __restrict__ ei, int* __restrict__ cur,
                       int* __restrict__ csr, int E) {
    int e = blockIdx.x * blockDim.x + threadIdx.x;
    if (e >= E) return;
    int c = ei[e], r = ei[E + e];
    if (r == c) return;
    int slot = atomicAdd(&cur[r], 1);
    csr[slot] = c;
}

// ---- Gather SpMM pass 1 (gate = cc[row], row-uniform): one wave per row, no atomics.
// Writes single acc buffer; channel selection deferred to dense1.
__global__ __launch_bounds__(256) void k_gather1(
        const int* __restrict__ off, const int* __restrict__ cur,
        const int* __restrict__ csr, const int* __restrict__ cc,
        const float* __restrict__ x,
        const float* __restrict__ dl, const float* __restrict__ dh,
        float* __restrict__ acc1, int n) {
    int w = (blockIdx.x * blockDim.x + threadIdx.x) >> 6;
    int lane = threadIdx.x & 63;
    if (w >= n) return;
    int r = w;
    int j0 = off[r], j1 = cur[r];
    int ccr = cc[r];
    const float* dd = ccr ? dl : dh;
    float a = 0.f;
    int j = j0;
    for (; j + 1 < j1; j += 2) {
        int c0 = csr[j], c1 = csr[j + 1];
        float w0 = dd[c0], w1 = dd[c1];
        float v0 = x[(c0 << 6) + lane];
        float v1 = x[(c1 << 6) + lane];
        a = fmaf(w0, v0, a);
        a = fmaf(w1, v1, a);
    }
    if (j < j1) {
        int c0 = csr[j];
        a = fmaf(dd[c0], x[(c0 << 6) + lane], a);
    }
    float dr = ccr ? dl[r] : dh[r];
    acc1[(r << 6) + lane] = dr * a;
}

// ---- Dense layer 1: 4 GEMVs with weights in LDS (packed float2), channel select by cc[row].
__global__ __launch_bounds__(512) void k_dense1(
        const float* __restrict__ x, const float* __restrict__ acc1,
        const int* __restrict__ cc,
        const float* __restrict__ dl, const float* __restrict__ dh,
        const float* __restrict__ W1l, const float* __restrict__ W1r,
        const float* __restrict__ W3l, const float* __restrict__ W3r,
        float* __restrict__ XL, float* __restrict__ XH, int n) {
    __shared__ float2 sA[4096];  // {W1l, W1r}
    __shared__ float2 sB[4096];  // {W3l, W3r}
    for (int idx = threadIdx.x; idx < 4096; idx += 512) {
        sA[idx] = make_float2(W1l[idx], W1r[idx]);
        sB[idx] = make_float2(W3l[idx], W3r[idx]);
    }
    __syncthreads();
    int lane = threadIdx.x & 63, wid = threadIdx.x >> 6;
    for (int i = blockIdx.x * 8 + wid; i < n; i += gridDim.x * 8) {
        int ccr = cc[i];
        float dli = dl[i]; dli *= dli;
        float dhi = dh[i]; dhi *= dhi;
        const float4* xi4 = (const float4*)(x + (i << 6));
        const float4* a4  = (const float4*)(acc1 + (i << 6));
        float sl = 0.f, sh = 0.f;
        #pragma unroll
        for (int k4 = 0; k4 < 16; ++k4) {
            float4 xv4 = xi4[k4];
            float4 av4 = a4[k4];
            #pragma unroll
            for (int j = 0; j < 4; ++j) {
                int k = (k4 << 2) + j;
                float xv = COMP(xv4, j);
                float av = COMP(av4, j);
                float al = fmaf(dli, xv, ccr ? av : 0.f);
                float ah = fmaf(dhi, xv, ccr ? 0.f : av);
                float2 wA = sA[(k << 6) + lane];
                float2 wB = sB[(k << 6) + lane];
                sl = fmaf(al, wA.x, fmaf(xv, wA.y, sl));
                sh = fmaf(ah, wB.x, fmaf(xv, wB.y, sh));
            }
        }
        XL[(i << 6) + lane] = fmaxf(sl, 0.f);
        XH[(i << 6) + lane] = fmaxf(sh, 0.f);
    }
}

// ---- Gather SpMM pass 2 (gate = cc[col], mixed per row): two register accumulators.
__global__ __launch_bounds__(256) void k_gather2(
        const int* __restrict__ off, const int* __restrict__ cur,
        const int* __restrict__ csr, const int* __restrict__ cc,
        const float* __restrict__ XL, const float* __restrict__ XH,
        const float* __restrict__ dll, const float* __restrict__ dhh,
        float* __restrict__ accL, float* __restrict__ accH, int n) {
    int w = (blockIdx.x * blockDim.x + threadIdx.x) >> 6;
    int lane = threadIdx.x & 63;
    if (w >= n) return;
    int r = w;
    int j0 = off[r], j1 = cur[r];
    float aL = 0.f, aH = 0.f;
    int j = j0;
    for (; j + 1 < j1; j += 2) {
        int c0 = csr[j], c1 = csr[j + 1];
        if (cc[c0]) aL = fmaf(dll[c0], XL[(c0 << 6) + lane], aL);
        else        aH = fmaf(dhh[c0], XH[(c0 << 6) + lane], aH);
        if (cc[c1]) aL = fmaf(dll[c1], XL[(c1 << 6) + lane], aL);
        else        aH = fmaf(dhh[c1], XH[(c1 << 6) + lane], aH);
    }
    if (j < j1) {
        int c0 = csr[j];
        if (cc[c0]) aL = fmaf(dll[c0], XL[(c0 << 6) + lane], aL);
        else        aH = fmaf(dhh[c0], XH[(c0 << 6) + lane], aH);
    }
    accL[(r << 6) + lane] = dll[r] * aL;
    accH[(r << 6) + lane] = dhh[r] * aH;
}

// ---- Dense layer 2 part A: tmp = laml*sl + lamh*sh (4 GEMVs, 64KB LDS).
// Writes in-place over accL (row read fully before the single store; same thread).
__global__ __launch_bounds__(512) void k_dense2a(
        const float* __restrict__ XL, const float* __restrict__ XH,
        float* accLtmp,                       // accL in, tmp out (aliased on purpose)
        const float* __restrict__ accH,
        const float* __restrict__ dll, const float* __restrict__ dhh,
        const float* __restrict__ W2l, const float* __restrict__ W2r,
        const float* __restrict__ W4l, const float* __restrict__ W4r,
        const float* __restrict__ lam1, const float* __restrict__ lam2, int n) {
    __shared__ float2 sA[4096];  // {W2l, W2r}
    __shared__ float2 sB[4096];  // {W4l, W4r}
    for (int idx = threadIdx.x; idx < 4096; idx += 512) {
        sA[idx] = make_float2(W2l[idx], W2r[idx]);
        sB[idx] = make_float2(W4l[idx], W4r[idx]);
    }
    __syncthreads();
    float e0 = __expf(lam1[0]), e1 = __expf(lam1[1]);
    float laml = e1 / (e0 + e1);
    float g0 = __expf(lam2[0]), g1 = __expf(lam2[1]);
    float lamh = g1 / (g0 + g1);
    int lane = threadIdx.x & 63, wid = threadIdx.x >> 6;
    for (int i = blockIdx.x * 8 + wid; i < n; i += gridDim.x * 8) {
        float dlli = dll[i]; dlli *= dlli;
        float dhhi = dhh[i]; dhhi *= dhhi;
        const float4* xl4 = (const float4*)(XL + (i << 6));
        const float4* xh4 = (const float4*)(XH + (i << 6));
        const float4* aL4 = (const float4*)(accLtmp + (i << 6));
        const float4* aH4 = (const float4*)(accH + (i << 6));
        float sl = 0.f, sh = 0.f;
        #pragma unroll
        for (int k4 = 0; k4 < 16; ++k4) {
            float4 xlv4 = xl4[k4], xhv4 = xh4[k4];
            float4 alv4 = aL4[k4], ahv4 = aH4[k4];
            #pragma unroll
            for (int j = 0; j < 4; ++j) {
                int k = (k4 << 2) + j;
                float xlv = COMP(xlv4, j), xhv = COMP(xhv4, j);
                float al = fmaf(dlli, xlv, COMP(alv4, j));
                float ah = fmaf(dhhi, xhv, COMP(ahv4, j));
                float2 wA = sA[(k << 6) + lane];
                float2 wB = sB[(k << 6) + lane];
                sl = fmaf(al, wA.x, fmaf(xlv, wA.y, sl));
                sh = fmaf(ah, wB.x, fmaf(xhv, wB.y, sh));
            }
        }
        accLtmp[(i << 6) + lane] = laml * sl + lamh * sh;
    }
}

// ---- Dense layer 2 part B: xm GEMV + lambda mix + ReLU + 64->C projection, write out.
__global__ __launch_bounds__(512) void k_dense2b(
        const float* __restrict__ x, const float* __restrict__ tmp,
        const int* __restrict__ cc,
        const float* __restrict__ WX,
        const float* __restrict__ lam1, const float* __restrict__ lam2,
        const float* __restrict__ linW, const float* __restrict__ linb,
        float* __restrict__ out, int n, int C) {
    __shared__ float sWX[4096];
    __shared__ float sLW[64 * 64 + 64];
    __shared__ float sLB[64];
    for (int idx = threadIdx.x; idx < 4096; idx += 512) sWX[idx] = WX[idx];
    int nLW = 64 * C + 64;
    for (int idx = threadIdx.x; idx < nLW; idx += 512)
        sLW[idx] = (idx < 64 * C) ? linW[idx] : 0.f;
    if (threadIdx.x < 64) sLB[threadIdx.x] = (threadIdx.x < C) ? linb[threadIdx.x] : 0.f;
    __syncthreads();
    float e0 = __expf(lam1[0]), e1 = __expf(lam1[1]);
    float lamxl = e0 / (e0 + e1);
    float g0 = __expf(lam2[0]), g1 = __expf(lam2[1]);
    float lamxh = g0 / (g0 + g1);
    int lane = threadIdx.x & 63, wid = threadIdx.x >> 6;
    for (int i = blockIdx.x * 8 + wid; i < n; i += gridDim.x * 8) {
        float c = (float)cc[i];
        float lamx = lamxl * c + lamxh * (1.f - c);
        const float4* xi4 = (const float4*)(x + (i << 6));
        float sm = 0.f;
        #pragma unroll
        for (int k4 = 0; k4 < 16; ++k4) {
            float4 xv4 = xi4[k4];
            #pragma unroll
            for (int j = 0; j < 4; ++j) {
                int k = (k4 << 2) + j;
                sm = fmaf(COMP(xv4, j), sWX[(k << 6) + lane], sm);
            }
        }
        float xf = fmaxf(fmaf(lamx, sm, tmp[(i << 6) + lane]), 0.f);
        // wave-local 64 -> C projection via shuffles (no smem staging needed)
        float s = sLB[lane];
        #pragma unroll
        for (int k = 0; k < 64; ++k) {
            float xv = __shfl(xf, k, 64);
            s = fmaf(xv, sLW[k * C + lane], s);
        }
        if (lane < C) out[i * C + lane] = s;
    }
}

extern "C" void kernel_launch(void* const* d_in, const int* in_sizes, int n_in,
                              void* d_out, int out_size, void* d_ws, size_t ws_size,
                              hipStream_t stream) {
    const float* x    = (const float*)d_in[0];
    const int*   ei   = (const int*)d_in[1];
    const int*   cc   = (const int*)d_in[2];
    const float* W1l  = (const float*)d_in[3];
    const float* W1r  = (const float*)d_in[4];
    const float* W2l  = (const float*)d_in[5];
    const float* W2r  = (const float*)d_in[6];
    const float* W3l  = (const float*)d_in[7];
    const float* W3r  = (const float*)d_in[8];
    const float* W4l  = (const float*)d_in[9];
    const float* W4r  = (const float*)d_in[10];
    const float* WX   = (const float*)d_in[11];
    const float* lam1 = (const float*)d_in[12];
    const float* lam2 = (const float*)d_in[13];
    const float* linW = (const float*)d_in[14];
    const float* linb = (const float*)d_in[15];

    int n = in_sizes[2];
    int E = in_sizes[1] / 2;
    int C = in_sizes[15];

    char* ws = (char*)d_ws;
    size_t nf = (size_t)n * 64 * sizeof(float);
    float* bufA = (float*)ws; ws += nf;   // acc1 (pass1) / accL (pass2) / tmp (2a out)
    float* bufB = (float*)ws; ws += nf;   // accH (pass2)
    float* XLb  = (float*)ws; ws += nf;
    float* XHb  = (float*)ws; ws += nf;
    float* dl   = (float*)ws; ws += (size_t)n * sizeof(float);
    float* dh   = (float*)ws; ws += (size_t)n * sizeof(float);
    float* dll  = (float*)ws; ws += (size_t)n * sizeof(float);
    float* dhh  = (float*)ws; ws += (size_t)n * sizeof(float);
    unsigned long long* deg = (unsigned long long*)ws; ws += (size_t)n * sizeof(unsigned long long);
    int* off = (int*)ws; ws += (size_t)n * sizeof(int);
    int* cur = (int*)ws; ws += (size_t)n * sizeof(int);
    unsigned* total = (unsigned*)ws; ws += 256;   // padded
    int* csr = (int*)ws; ws += (size_t)E * sizeof(int);

    hipMemsetAsync(deg, 0, (size_t)n * sizeof(unsigned long long), stream);
    hipMemsetAsync(total, 0, 256, stream);

    k_deg<<<(E + 255) / 256, 256, 0, stream>>>(ei, cc, deg, E);
    k_dinv_alloc<<<(n + 255) / 256, 256, 0, stream>>>(deg, cc, dl, dh, dll, dhh,
                                                      off, cur, total, n);
    k_fill<<<(E + 255) / 256, 256, 0, stream>>>(ei, cur, csr, E);

    int gatherBlocks = (n + 3) / 4;   // 4 waves per 256-thread block, 1 wave per row
    k_gather1<<<gatherBlocks, 256, 0, stream>>>(off, cur, csr, cc, x, dl, dh, bufA, n);
    k_dense1<<<512, 512, 0, stream>>>(x, bufA, cc, dl, dh, W1l, W1r, W3l, W3r, XLb, XHb, n);
    k_gather2<<<gatherBlocks, 256, 0, stream>>>(off, cur, csr, cc, XLb, XHb, dll, dhh,
                                                bufA, bufB, n);
    k_dense2a<<<512, 512, 0, stream>>>(XLb, XHb, bufA, bufB, dll, dhh,
                                       W2l, W2r, W4l, W4r, lam1, lam2, n);
    k_dense2b<<<1024, 512, 0, stream>>>(x, bufA, cc, WX, lam1, lam2, linW, linb,
                                        (float*)d_out, n, C);
}

// Round 4
// 1126.727 us; speedup vs baseline: 1.7560x; 1.7560x over previous
//
#include <hip/hip_runtime.h>

#define COMP(v,j) ((j)==0?(v).x:((j)==1?(v).y:((j)==2?(v).z:(v).w)))

// ---- Pass 1: per-row degree counters: hi32 = #non-self edges, lo32 = sum cc[col]
__global__ void k_deg(const int* __restrict__ ei, const int* __restrict__ cc,
                      unsigned long long* __restrict__ deg, int E) {
    int e = blockIdx.x * blockDim.x + threadIdx.x;
    if (e >= E) return;
    int c = ei[e];       // col = edge_index[0]
    int r = ei[E + e];   // row = edge_index[1]
    if (r != c) {
        unsigned long long add = 0x100000000ULL + (unsigned long long)(cc[c] & 1);
        atomicAdd(&deg[r], add);
    }
}

// ---- Pass 2: D^-0.5 for the 4 norms + CSR offset allocation (wave scan, 1 atomic/wave)
__global__ void k_dinv_alloc(const unsigned long long* __restrict__ deg,
                             const int* __restrict__ cc,
                             float* __restrict__ dl, float* __restrict__ dh,
                             float* __restrict__ dll, float* __restrict__ dhh,
                             int* __restrict__ off, int* __restrict__ cur,
                             unsigned* __restrict__ total, int n) {
    int i = blockIdx.x * blockDim.x + threadIdx.x;
    int lane = threadIdx.x & 63;
    unsigned long long d = (i < n) ? deg[i] : 0ULL;
    int cnt = (int)(d >> 32);
    int ccs = (int)(d & 0xffffffffULL);
    if (i < n) {
        float c = (float)cc[i];
        float fc = (float)cnt, fs = (float)ccs;
        dl[i]  = rsqrtf(c * fc + 1.0f);
        dh[i]  = rsqrtf((1.0f - c) * fc + 1.0f);
        dll[i] = rsqrtf(fs + 1.0f);
        dhh[i] = rsqrtf(fc - fs + 1.0f);
    }
    int s = cnt;
    #pragma unroll
    for (int dlt = 1; dlt < 64; dlt <<= 1) {
        int t = __shfl_up(s, dlt, 64);
        if (lane >= dlt) s += t;
    }
    int wtot = __shfl(s, 63, 64);
    unsigned base = 0;
    if (lane == 0) base = atomicAdd(total, (unsigned)wtot);
    base = __shfl(base, 0, 64);
    if (i < n) {
        int o = (int)base + s - cnt;
        off[i] = o;
        cur[i] = o;
    }
}

// ---- CSR fill
__global__ void k_fill(const int* __restrict__ ei, int* __restrict__ cur,
                       int* __restrict__ csr, int E) {
    int e = blockIdx.x * blockDim.x + threadIdx.x;
    if (e >= E) return;
    int c = ei[e], r = ei[E + e];
    if (r == c) return;
    int slot = atomicAdd(&cur[r], 1);
    csr[slot] = c;
}

// ---- Gather SpMM pass 1 (gate = cc[row], row-uniform)
__global__ __launch_bounds__(256) void k_gather1(
        const int* __restrict__ off, const int* __restrict__ cur,
        const int* __restrict__ csr, const int* __restrict__ cc,
        const float* __restrict__ x,
        const float* __restrict__ dl, const float* __restrict__ dh,
        float* __restrict__ acc1, int n) {
    int w = (blockIdx.x * blockDim.x + threadIdx.x) >> 6;
    int lane = threadIdx.x & 63;
    if (w >= n) return;
    int r = w;
    int j0 = off[r], j1 = cur[r];
    int ccr = cc[r];
    const float* dd = ccr ? dl : dh;
    float a = 0.f;
    int j = j0;
    for (; j + 1 < j1; j += 2) {
        int c0 = csr[j], c1 = csr[j + 1];
        float w0 = dd[c0], w1 = dd[c1];
        float v0 = x[(c0 << 6) + lane];
        float v1 = x[(c1 << 6) + lane];
        a = fmaf(w0, v0, a);
        a = fmaf(w1, v1, a);
    }
    if (j < j1) {
        int c0 = csr[j];
        a = fmaf(dd[c0], x[(c0 << 6) + lane], a);
    }
    float dr = ccr ? dl[r] : dh[r];
    acc1[(r << 6) + lane] = dr * a;
}

// ---- Gather SpMM pass 2 (gate = cc[col])
__global__ __launch_bounds__(256) void k_gather2(
        const int* __restrict__ off, const int* __restrict__ cur,
        const int* __restrict__ csr, const int* __restrict__ cc,
        const float* __restrict__ XL, const float* __restrict__ XH,
        const float* __restrict__ dll, const float* __restrict__ dhh,
        float* __restrict__ accL, float* __restrict__ accH, int n) {
    int w = (blockIdx.x * blockDim.x + threadIdx.x) >> 6;
    int lane = threadIdx.x & 63;
    if (w >= n) return;
    int r = w;
    int j0 = off[r], j1 = cur[r];
    float aL = 0.f, aH = 0.f;
    for (int j = j0; j < j1; ++j) {
        int c0 = csr[j];
        if (cc[c0]) aL = fmaf(dll[c0], XL[(c0 << 6) + lane], aL);
        else        aH = fmaf(dhh[c0], XH[(c0 << 6) + lane], aH);
    }
    accL[(r << 6) + lane] = dll[r] * aL;
    accH[(r << 6) + lane] = dhh[r] * aH;
}

// ---- Dense layer 1: tiles in LDS, weight COLUMNS in registers.
// Block = 4 waves over a 64-node tile: waves 0,1 = L channel (W1l,W1r),
// waves 2,3 = H channel (W3l,W3r). Lane = output feature.
__global__ __launch_bounds__(256) void k_dense1(
        const float* __restrict__ x, const float* __restrict__ acc1,
        const int* __restrict__ cc,
        const float* __restrict__ dl, const float* __restrict__ dh,
        const float* __restrict__ W1l, const float* __restrict__ W1r,
        const float* __restrict__ W3l, const float* __restrict__ W3r,
        float* __restrict__ XL, float* __restrict__ XH, int n) {
    __shared__ float sX[64 * 64];
    __shared__ float sA[64 * 64];
    __shared__ float sDL[64];
    __shared__ float sDH[64];
    __shared__ int   sCC[64];
    int b = blockIdx.x;
    int lane = threadIdx.x & 63, w = threadIdx.x >> 6;
    // cooperative coalesced tile load
    const float4* x4 = (const float4*)x;
    const float4* a4 = (const float4*)acc1;
    int base4 = b * 1024, lim4 = n * 16;
    #pragma unroll
    for (int t = 0; t < 4; ++t) {
        int i4 = base4 + t * 256 + threadIdx.x;
        float4 vx = make_float4(0.f, 0.f, 0.f, 0.f), va = vx;
        if (i4 < lim4) { vx = x4[i4]; va = a4[i4]; }
        ((float4*)sX)[t * 256 + threadIdx.x] = vx;
        ((float4*)sA)[t * 256 + threadIdx.x] = va;
    }
    if (threadIdx.x < 64) {
        int i = b * 64 + threadIdx.x;
        int c = (i < n) ? cc[i] : 0;
        float a = (i < n) ? dl[i] : 0.f;
        float h = (i < n) ? dh[i] : 0.f;
        sCC[threadIdx.x] = c;
        sDL[threadIdx.x] = a * a;
        sDH[threadIdx.x] = h * h;
    }
    // weight columns -> registers (64 coalesced dword loads per matrix)
    int ch = w >> 1;                       // 0 = L, 1 = H
    const float* Wl = ch ? W3l : W1l;
    const float* Wr = ch ? W3r : W1r;
    float wl[64], wr[64];
    #pragma unroll
    for (int k = 0; k < 64; ++k) {
        wl[k] = Wl[(k << 6) + lane];
        wr[k] = Wr[(k << 6) + lane];
    }
    __syncthreads();
    int sub = w & 1;
    float* OUT = ch ? XH : XL;
    for (int m = 0; m < 32; ++m) {
        int j = sub * 32 + m;
        int i = b * 64 + j;
        if (i >= n) break;
        float dsq = ch ? sDH[j] : sDL[j];
        int ccr = sCC[j];
        float gate = ch ? (ccr ? 0.f : 1.f) : (ccr ? 1.f : 0.f);
        const float4* rx = (const float4*)(sX + (j << 6));
        const float4* ra = (const float4*)(sA + (j << 6));
        float s = 0.f;
        #pragma unroll
        for (int k4 = 0; k4 < 16; ++k4) {
            float4 xv4 = rx[k4];
            float4 av4 = ra[k4];
            #pragma unroll
            for (int jj = 0; jj < 4; ++jj) {
                int k = (k4 << 2) + jj;
                float xv = COMP(xv4, jj);
                float agg = fmaf(dsq, xv, gate * COMP(av4, jj));
                s = fmaf(agg, wl[k], s);
                s = fmaf(xv, wr[k], s);
            }
        }
        OUT[(i << 6) + lane] = fmaxf(s, 0.f);
    }
}

// ---- Dense layer 2, one channel: tmp = scale * (Wl@(acc + d^2*Xc) + Wr@Xc).
// All 4 waves same channel, 16 nodes each. Writes tmp in place over acc.
__global__ __launch_bounds__(256) void k_dense2ch(
        const float* __restrict__ Xc, float* __restrict__ accC,
        const float* __restrict__ dd,
        const float* __restrict__ Wl, const float* __restrict__ Wr,
        const float* __restrict__ lam, int n) {
    __shared__ float sX[64 * 64];
    __shared__ float sA[64 * 64];
    __shared__ float sD[64];
    int b = blockIdx.x;
    int lane = threadIdx.x & 63, w = threadIdx.x >> 6;
    const float4* x4 = (const float4*)Xc;
    const float4* a4 = (const float4*)accC;
    int base4 = b * 1024, lim4 = n * 16;
    #pragma unroll
    for (int t = 0; t < 4; ++t) {
        int i4 = base4 + t * 256 + threadIdx.x;
        float4 vx = make_float4(0.f, 0.f, 0.f, 0.f), va = vx;
        if (i4 < lim4) { vx = x4[i4]; va = a4[i4]; }
        ((float4*)sX)[t * 256 + threadIdx.x] = vx;
        ((float4*)sA)[t * 256 + threadIdx.x] = va;
    }
    if (threadIdx.x < 64) {
        int i = b * 64 + threadIdx.x;
        float a = (i < n) ? dd[i] : 0.f;
        sD[threadIdx.x] = a * a;
    }
    float wlr[64], wrr[64];
    #pragma unroll
    for (int k = 0; k < 64; ++k) {
        wlr[k] = Wl[(k << 6) + lane];
        wrr[k] = Wr[(k << 6) + lane];
    }
    float e0 = __expf(lam[0]), e1 = __expf(lam[1]);
    float scale = e1 / (e0 + e1);
    __syncthreads();
    for (int m = 0; m < 16; ++m) {
        int j = w * 16 + m;
        int i = b * 64 + j;
        if (i >= n) break;
        float dsq = sD[j];
        const float4* rx = (const float4*)(sX + (j << 6));
        const float4* ra = (const float4*)(sA + (j << 6));
        float s = 0.f;
        #pragma unroll
        for (int k4 = 0; k4 < 16; ++k4) {
            float4 xv4 = rx[k4];
            float4 av4 = ra[k4];
            #pragma unroll
            for (int jj = 0; jj < 4; ++jj) {
                int k = (k4 << 2) + jj;
                float xv = COMP(xv4, jj);
                float agg = fmaf(dsq, xv, COMP(av4, jj));
                s = fmaf(agg, wlr[k], s);
                s = fmaf(xv, wrr[k], s);
            }
        }
        accC[(i << 6) + lane] = scale * s;   // tmp over acc (block-local rows)
    }
}

// ---- Final: sm = x@WX, xf = relu(lamx*sm + tmpL + tmpH), out = xf@linW + b.
// x tile in LDS; WX / linW columns in registers; per-wave LDS scratch row for
// the 64->C projection (instead of 64 shuffles).
__global__ __launch_bounds__(256) void k_dense2b(
        const float* __restrict__ x,
        const float* __restrict__ tmpL, const float* __restrict__ tmpH,
        const int* __restrict__ cc,
        const float* __restrict__ WX,
        const float* __restrict__ lam1, const float* __restrict__ lam2,
        const float* __restrict__ linW, const float* __restrict__ linb,
        float* __restrict__ out, int n, int C) {
    __shared__ float sX[64 * 64];
    __shared__ float sXF[4][64];
    __shared__ int sCC[64];
    int b = blockIdx.x;
    int lane = threadIdx.x & 63, w = threadIdx.x >> 6;
    const float4* x4 = (const float4*)x;
    int base4 = b * 1024, lim4 = n * 16;
    #pragma unroll
    for (int t = 0; t < 4; ++t) {
        int i4 = base4 + t * 256 + threadIdx.x;
        float4 vx = make_float4(0.f, 0.f, 0.f, 0.f);
        if (i4 < lim4) vx = x4[i4];
        ((float4*)sX)[t * 256 + threadIdx.x] = vx;
    }
    if (threadIdx.x < 64) {
        int i = b * 64 + threadIdx.x;
        sCC[threadIdx.x] = (i < n) ? cc[i] : 0;
    }
    float wx[64], lw[64];
    #pragma unroll
    for (int k = 0; k < 64; ++k) {
        wx[k] = WX[(k << 6) + lane];
        lw[k] = (lane < C) ? linW[k * C + lane] : 0.f;
    }
    float e0 = __expf(lam1[0]), e1 = __expf(lam1[1]);
    float lamxl = e0 / (e0 + e1);
    float g0 = __expf(lam2[0]), g1 = __expf(lam2[1]);
    float lamxh = g0 / (g0 + g1);
    float bias = (lane < C) ? linb[lane] : 0.f;
    __syncthreads();
    for (int m = 0; m < 16; ++m) {
        int j = w * 16 + m;
        int i = b * 64 + j;
        if (i >= n) break;
        float lamx = sCC[j] ? lamxl : lamxh;
        const float4* rx = (const float4*)(sX + (j << 6));
        float s = 0.f;
        #pragma unroll
        for (int k4 = 0; k4 < 16; ++k4) {
            float4 xv4 = rx[k4];
            #pragma unroll
            for (int jj = 0; jj < 4; ++jj)
                s = fmaf(COMP(xv4, jj), wx[(k4 << 2) + jj], s);
        }
        float tsum = tmpL[(i << 6) + lane] + tmpH[(i << 6) + lane];
        float xf = fmaxf(fmaf(lamx, s, tsum), 0.f);
        sXF[w][lane] = xf;                 // same-wave LDS RAW: compiler waits
        float o = bias;
        #pragma unroll
        for (int k4 = 0; k4 < 16; ++k4) {
            float4 v = ((const float4*)sXF[w])[k4];
            o = fmaf(v.x, lw[(k4 << 2) + 0], o);
            o = fmaf(v.y, lw[(k4 << 2) + 1], o);
            o = fmaf(v.z, lw[(k4 << 2) + 2], o);
            o = fmaf(v.w, lw[(k4 << 2) + 3], o);
        }
        if (lane < C) out[i * C + lane] = o;
    }
}

extern "C" void kernel_launch(void* const* d_in, const int* in_sizes, int n_in,
                              void* d_out, int out_size, void* d_ws, size_t ws_size,
                              hipStream_t stream) {
    const float* x    = (const float*)d_in[0];
    const int*   ei   = (const int*)d_in[1];
    const int*   cc   = (const int*)d_in[2];
    const float* W1l  = (const float*)d_in[3];
    const float* W1r  = (const float*)d_in[4];
    const float* W2l  = (const float*)d_in[5];
    const float* W2r  = (const float*)d_in[6];
    const float* W3l  = (const float*)d_in[7];
    const float* W3r  = (const float*)d_in[8];
    const float* W4l  = (const float*)d_in[9];
    const float* W4r  = (const float*)d_in[10];
    const float* WX   = (const float*)d_in[11];
    const float* lam1 = (const float*)d_in[12];
    const float* lam2 = (const float*)d_in[13];
    const float* linW = (const float*)d_in[14];
    const float* linb = (const float*)d_in[15];

    int n = in_sizes[2];
    int E = in_sizes[1] / 2;
    int C = in_sizes[15];

    char* ws = (char*)d_ws;
    size_t nf = (size_t)n * 64 * sizeof(float);
    float* bufA = (float*)ws; ws += nf;   // acc1 / accL / tmpL
    float* bufB = (float*)ws; ws += nf;   // accH / tmpH
    float* XLb  = (float*)ws; ws += nf;
    float* XHb  = (float*)ws; ws += nf;
    float* dl   = (float*)ws; ws += (size_t)n * sizeof(float);
    float* dh   = (float*)ws; ws += (size_t)n * sizeof(float);
    float* dll  = (float*)ws; ws += (size_t)n * sizeof(float);
    float* dhh  = (float*)ws; ws += (size_t)n * sizeof(float);
    unsigned long long* deg = (unsigned long long*)ws; ws += (size_t)n * sizeof(unsigned long long);
    int* off = (int*)ws; ws += (size_t)n * sizeof(int);
    int* cur = (int*)ws; ws += (size_t)n * sizeof(int);
    unsigned* total = (unsigned*)ws; ws += 256;
    int* csr = (int*)ws; ws += (size_t)E * sizeof(int);

    hipMemsetAsync(deg, 0, (size_t)n * sizeof(unsigned long long), stream);
    hipMemsetAsync(total, 0, 256, stream);

    k_deg<<<(E + 255) / 256, 256, 0, stream>>>(ei, cc, deg, E);
    k_dinv_alloc<<<(n + 255) / 256, 256, 0, stream>>>(deg, cc, dl, dh, dll, dhh,
                                                      off, cur, total, n);
    k_fill<<<(E + 255) / 256, 256, 0, stream>>>(ei, cur, csr, E);

    int gatherBlocks = (n + 3) / 4;
    int nb = (n + 63) / 64;
    k_gather1<<<gatherBlocks, 256, 0, stream>>>(off, cur, csr, cc, x, dl, dh, bufA, n);
    k_dense1<<<nb, 256, 0, stream>>>(x, bufA, cc, dl, dh, W1l, W1r, W3l, W3r, XLb, XHb, n);
    k_gather2<<<gatherBlocks, 256, 0, stream>>>(off, cur, csr, cc, XLb, XHb, dll, dhh,
                                                bufA, bufB, n);
    k_dense2ch<<<nb, 256, 0, stream>>>(XLb, bufA, dll, W2l, W2r, lam1, n);
    k_dense2ch<<<nb, 256, 0, stream>>>(XHb, bufB, dhh, W4l, W4r, lam2, n);
    k_dense2b<<<nb, 256, 0, stream>>>(x, bufA, bufB, cc, WX, lam1, lam2, linW, linb,
                                      (float*)d_out, n, C);
}